// Round 2
// baseline (915.614 us; speedup 1.0000x reference)
//
#include <hip/hip_runtime.h>
#include <hip/hip_fp16.h>

// GATLayer: out[b,o,m] = relu( bm[o] + sum_n Y[b,o,n] * att[b,m,n] )
//   Y = wm @ x[b]            (O x N)
//   att[b,m,n] = softmax_n( leaky(q[b,n] + k[b,m]) ),  q = wq.x, k = wk.x
// leaky is monotone -> row max M_m = leaky(qmax_b + k_m); att row is a closed
// form of q,k -> synthesized on the fly inside the second GEMM (never stored).
//
// ws layout (must fit in ws_size): q,k,invZ: 3*B*N f32 = 384 KB; qmax: 256 B;
// Y: B*O*N fp16 = 32 MiB. Total ~32.4 MiB (out itself is 64 MiB).

constexpr int B = 32, C = 512, N = 1024, O = 512;
constexpr float SLOPE = 0.01f;

typedef _Float16 half4 __attribute__((ext_vector_type(4)));

__device__ __forceinline__ float leaky(float s) { return s > 0.f ? s : SLOPE * s; }

// ---------------- K1: q[b,n], k[b,n] ----------------
__global__ __launch_bounds__(256) void qk_kernel(const float* __restrict__ x,
    const float* __restrict__ wq, const float* __restrict__ wk,
    float* __restrict__ q, float* __restrict__ k) {
  int b = blockIdx.y;
  int n = blockIdx.x * 256 + threadIdx.x;
  const float* xp = x + (size_t)b * C * N + n;
  float aq = 0.f, ak = 0.f;
#pragma unroll 8
  for (int c = 0; c < C; ++c) {
    float v = xp[(size_t)c * N];
    aq += wq[c] * v;
    ak += wk[c] * v;
  }
  q[b * N + n] = aq;
  k[b * N + n] = ak;
}

// ---------------- K2: qmax[b] ----------------
__global__ __launch_bounds__(256) void qmax_kernel(const float* __restrict__ q,
                                                   float* __restrict__ qmax) {
  int b = blockIdx.x;
  int tid = threadIdx.x;
  float m = -1e30f;
  for (int n = tid; n < N; n += 256) m = fmaxf(m, q[b * N + n]);
#pragma unroll
  for (int off = 32; off > 0; off >>= 1) m = fmaxf(m, __shfl_down(m, off, 64));
  __shared__ float red[4];
  if ((tid & 63) == 0) red[tid >> 6] = m;
  __syncthreads();
  if (tid == 0) qmax[b] = fmaxf(fmaxf(red[0], red[1]), fmaxf(red[2], red[3]));
}

// ---------------- K3: invZ[b,m] = 1 / sum_n exp(leaky(q_n+k_m) - M_m) -------
__global__ __launch_bounds__(256) void z_kernel(const float* __restrict__ q,
    const float* __restrict__ k, const float* __restrict__ qmax,
    float* __restrict__ invZ) {
  int b = blockIdx.y;
  int m = blockIdx.x * 256 + threadIdx.x;
  __shared__ float qs[N];
  for (int n = threadIdx.x; n < N; n += 256) qs[n] = q[b * N + n];
  __syncthreads();
  float km = k[b * N + m];
  float M = leaky(qmax[b] + km);
  float Z = 0.f;
#pragma unroll 8
  for (int n = 0; n < N; ++n) Z += __expf(leaky(qs[n] + km) - M);
  invZ[b * N + m] = 1.0f / Z;
}

// ---------------- K4: Y[b,o,n] = sum_c wm[o,c]*x[b,c,n]  (fp32 tiles, fp16 out)
__global__ __launch_bounds__(256) void gemm1_kernel(const float* __restrict__ x,
    const float* __restrict__ wm, _Float16* __restrict__ y) {
  __shared__ float As[16][68];  // [c][o]
  __shared__ float Bs[16][68];  // [c][n]
  int b = blockIdx.z;
  int o0 = blockIdx.y * 64;
  int n0 = blockIdx.x * 64;
  int t = threadIdx.x;
  int tn = t & 15, tm = t >> 4;
  float acc[4][4] = {};
  for (int c0 = 0; c0 < C; c0 += 16) {
    {
      int o_l = t >> 2, c_off = (t & 3) * 4;
      float4 v = *(const float4*)(wm + (size_t)(o0 + o_l) * C + c0 + c_off);
      As[c_off + 0][o_l] = v.x;
      As[c_off + 1][o_l] = v.y;
      As[c_off + 2][o_l] = v.z;
      As[c_off + 3][o_l] = v.w;
      int c_l = t >> 4, ncol = (t & 15) * 4;
      float4 w = *(const float4*)(x + ((size_t)b * C + c0 + c_l) * N + n0 + ncol);
      *(float4*)&Bs[c_l][ncol] = w;
    }
    __syncthreads();
#pragma unroll
    for (int kk = 0; kk < 16; ++kk) {
      float4 a = *(const float4*)&As[kk][tm * 4];
      float4 bb = *(const float4*)&Bs[kk][tn * 4];
      acc[0][0] += a.x * bb.x; acc[0][1] += a.x * bb.y; acc[0][2] += a.x * bb.z; acc[0][3] += a.x * bb.w;
      acc[1][0] += a.y * bb.x; acc[1][1] += a.y * bb.y; acc[1][2] += a.y * bb.z; acc[1][3] += a.y * bb.w;
      acc[2][0] += a.z * bb.x; acc[2][1] += a.z * bb.y; acc[2][2] += a.z * bb.z; acc[2][3] += a.z * bb.w;
      acc[3][0] += a.w * bb.x; acc[3][1] += a.w * bb.y; acc[3][2] += a.w * bb.z; acc[3][3] += a.w * bb.w;
    }
    __syncthreads();
  }
#pragma unroll
  for (int i = 0; i < 4; ++i) {
    int o = o0 + tm * 4 + i;
    half4 h;
    h.x = (_Float16)acc[i][0];
    h.y = (_Float16)acc[i][1];
    h.z = (_Float16)acc[i][2];
    h.w = (_Float16)acc[i][3];
    *(half4*)(y + ((size_t)b * O + o) * N + n0 + tn * 4) = h;
  }
}

// ---------------- K5: fused att-synthesis GEMM + bias + relu ----------------
// out[b,o,m] = relu(bm[o] + invZ_m * sum_n Y[o,n] * exp(leaky(q_n+k_m)-M_m))
__global__ __launch_bounds__(256) void gemm2f_kernel(const _Float16* __restrict__ y,
    const float* __restrict__ q, const float* __restrict__ k,
    const float* __restrict__ qmax, const float* __restrict__ invZ,
    const float* __restrict__ bm, float* __restrict__ out) {
  __shared__ float qs[N];       // full q row for this batch (4 KB)
  __shared__ float As[16][68];  // Y tile   [n][o]
  __shared__ float Es[16][68];  // exp tile [n][m]
  int b = blockIdx.z;
  int o0 = blockIdx.y * 64;
  int m0 = blockIdx.x * 64;
  int t = threadIdx.x;
  int tn = t & 15, tm = t >> 4;

  for (int n = t; n < N; n += 256) qs[n] = q[b * N + n];

  // this thread owns output columns m0 + tn*4 .. +3 (same cols for E synth)
  float km4[4], M4[4], iZ4[4];
  float qm = qmax[b];
#pragma unroll
  for (int j = 0; j < 4; ++j) {
    int m = m0 + tn * 4 + j;
    km4[j] = k[b * N + m];
    M4[j]  = leaky(qm + km4[j]);
    iZ4[j] = invZ[b * N + m];
  }
  __syncthreads();

  float acc[4][4] = {};
  for (int n0 = 0; n0 < N; n0 += 16) {
    {
      // stage Y tile: 16 n-rows x 64 o-cols
      int o_l = t >> 2, c_off = (t & 3) * 4;
      half4 v = *(const half4*)(y + ((size_t)b * O + o0 + o_l) * N + n0 + c_off);
      As[c_off + 0][o_l] = (float)v.x;
      As[c_off + 1][o_l] = (float)v.y;
      As[c_off + 2][o_l] = (float)v.z;
      As[c_off + 3][o_l] = (float)v.w;
      // synthesize E tile: row n_l = t>>4, cols tn*4..+3
      int n_l = t >> 4;
      float qn = qs[n0 + n_l];
#pragma unroll
      for (int j = 0; j < 4; ++j)
        Es[n_l][tn * 4 + j] = __expf(leaky(qn + km4[j]) - M4[j]);
    }
    __syncthreads();
#pragma unroll
    for (int kk = 0; kk < 16; ++kk) {
      float4 a = *(const float4*)&As[kk][tm * 4];
      float4 bb = *(const float4*)&Es[kk][tn * 4];
      acc[0][0] += a.x * bb.x; acc[0][1] += a.x * bb.y; acc[0][2] += a.x * bb.z; acc[0][3] += a.x * bb.w;
      acc[1][0] += a.y * bb.x; acc[1][1] += a.y * bb.y; acc[1][2] += a.y * bb.z; acc[1][3] += a.y * bb.w;
      acc[2][0] += a.z * bb.x; acc[2][1] += a.z * bb.y; acc[2][2] += a.z * bb.z; acc[2][3] += a.z * bb.w;
      acc[3][0] += a.w * bb.x; acc[3][1] += a.w * bb.y; acc[3][2] += a.w * bb.z; acc[3][3] += a.w * bb.w;
    }
    __syncthreads();
  }
#pragma unroll
  for (int i = 0; i < 4; ++i) {
    int o = o0 + tm * 4 + i;
    float bias = bm[o];
    float4 r;
    r.x = fmaxf(acc[i][0] * iZ4[0] + bias, 0.f);
    r.y = fmaxf(acc[i][1] * iZ4[1] + bias, 0.f);
    r.z = fmaxf(acc[i][2] * iZ4[2] + bias, 0.f);
    r.w = fmaxf(acc[i][3] * iZ4[3] + bias, 0.f);
    *(float4*)(out + ((size_t)b * O + o) * N + m0 + tn * 4) = r;
  }
}

extern "C" void kernel_launch(void* const* d_in, const int* in_sizes, int n_in,
                              void* d_out, int out_size, void* d_ws, size_t ws_size,
                              hipStream_t stream) {
  const float* x  = (const float*)d_in[0];
  const float* wq = (const float*)d_in[1];
  const float* wk = (const float*)d_in[2];
  const float* wm = (const float*)d_in[3];
  const float* bm = (const float*)d_in[4];
  float* out = (float*)d_out;

  // ws: q[B*N] | k[B*N] | invZ[B*N] | qmax[64]  (all f32)  | Y[B*O*N] f16
  float* q    = (float*)d_ws;
  float* k    = q + B * N;
  float* invZ = k + B * N;
  float* qmax = invZ + B * N;
  _Float16* y = (_Float16*)(qmax + 64);

  qk_kernel<<<dim3(N / 256, B), 256, 0, stream>>>(x, wq, wk, q, k);
  qmax_kernel<<<dim3(B), 256, 0, stream>>>(q, qmax);
  z_kernel<<<dim3(N / 256, B), 256, 0, stream>>>(q, k, qmax, invZ);
  gemm1_kernel<<<dim3(N / 64, O / 64, B), 256, 0, stream>>>(x, wm, y);
  gemm2f_kernel<<<dim3(N / 64, O / 64, B), 256, 0, stream>>>(y, q, k, qmax, invZ, bm, out);
}

// Round 3
// 244.569 us; speedup vs baseline: 3.7438x; 3.7438x over previous
//
#include <hip/hip_runtime.h>
#include <hip/hip_fp16.h>

// GATLayer on MI355X, MFMA fp16 version.
//   q = (wq.x)*log2e, k = (wk.x)*log2e                       [qk_kernel]
//   qmax_b = max_n q                                          [qmax_kernel]
//   E[m][n] = 2^( leaky(q_n + k_m) - M_m ),  M_m = leaky(qmax_b + k_m)
//   agg[c][m] = (1/Z_m) * sum_n x[c][n] * E[m][n]   -> aggT[m][c] fp16 [gemm_a]
//   out[o][m] = relu( bm[o] + sum_c aggT[m][c]*wm[o][c] )              [gemm_b]
// leaky(s)=max(s,0.01s); log2e folded into q,k so exp uses v_exp_f32 (2^x).
// Z is accumulated inside gemm_a (each thread's E slots partition n per m-row).

constexpr int B = 32, C = 512, N = 1024, O = 512;
constexpr float L2E = 1.4426950408889634f;

typedef _Float16 half8 __attribute__((ext_vector_type(8)));
typedef _Float16 half4v __attribute__((ext_vector_type(4)));
typedef float f32x4 __attribute__((ext_vector_type(4)));

#if __has_builtin(__builtin_amdgcn_exp2f)
#define EXP2(x) __builtin_amdgcn_exp2f(x)
#else
#define EXP2(x) exp2f(x)
#endif

__device__ __forceinline__ half8 cvt8(float4 a, float4 b) {
  half8 h;
  h[0] = (_Float16)a.x; h[1] = (_Float16)a.y; h[2] = (_Float16)a.z; h[3] = (_Float16)a.w;
  h[4] = (_Float16)b.x; h[5] = (_Float16)b.y; h[6] = (_Float16)b.z; h[7] = (_Float16)b.w;
  return h;
}

// ---------------- K1: q,k (scaled by log2e). 4-way c-split for occupancy. ----
__global__ __launch_bounds__(256) void qk_kernel(const float* __restrict__ x,
    const float* __restrict__ wq, const float* __restrict__ wk,
    float* __restrict__ q, float* __restrict__ k) {
  int b = blockIdx.y;
  int l = threadIdx.x & 63;
  int cq = threadIdx.x >> 6;          // which quarter of C this wave handles
  int n = blockIdx.x * 64 + l;
  const float* xp  = x + ((size_t)b * C + cq * 128) * N + n;
  const float* wqp = wq + cq * 128;
  const float* wkp = wk + cq * 128;
  float aq = 0.f, ak = 0.f;
#pragma unroll 8
  for (int c = 0; c < 128; ++c) {
    float v = xp[(size_t)c * N];
    aq += wqp[c] * v;
    ak += wkp[c] * v;
  }
  __shared__ float rq[4][64], rk[4][64];
  rq[cq][l] = aq;
  rk[cq][l] = ak;
  __syncthreads();
  if (threadIdx.x < 64) {
    float sq = (rq[0][l] + rq[1][l]) + (rq[2][l] + rq[3][l]);
    float sk = (rk[0][l] + rk[1][l]) + (rk[2][l] + rk[3][l]);
    q[b * N + blockIdx.x * 64 + l] = L2E * sq;
    k[b * N + blockIdx.x * 64 + l] = L2E * sk;
  }
}

// ---------------- K2: qmax[b] ----------------
__global__ __launch_bounds__(256) void qmax_kernel(const float* __restrict__ q,
                                                   float* __restrict__ qmax) {
  int b = blockIdx.x;
  int tid = threadIdx.x;
  float m = -1e30f;
  for (int n = tid; n < N; n += 256) m = fmaxf(m, q[b * N + n]);
#pragma unroll
  for (int off = 32; off > 0; off >>= 1) m = fmaxf(m, __shfl_down(m, off, 64));
  __shared__ float red[4];
  if ((tid & 63) == 0) red[tid >> 6] = m;
  __syncthreads();
  if (tid == 0) qmax[b] = fmaxf(fmaxf(red[0], red[1]), fmaxf(red[2], red[3]));
}

// ---------------- K3: gemm_a  aggT[m][c] = invZ_m * sum_n x[c][n]*E[m][n] ----
// Block tile: 128 c (M=c via A=x) x 128 m (N-dim via B=E), K=n, BK=32.
// 4 waves 2x2. LDS rows padded to 40 fp16 (80B) for bank spread.
__global__ __launch_bounds__(256) void gemm_a_kernel(const float* __restrict__ x,
    const float* __restrict__ q, const float* __restrict__ k,
    const float* __restrict__ qmax, _Float16* __restrict__ aggT) {
  __shared__ __align__(16) _Float16 As[128 * 40];  // x tile  [c][32n]
  __shared__ __align__(16) _Float16 Es[128 * 40];  // E tile  [m][32n]
  __shared__ __align__(16) float qs[N];
  __shared__ float izs[128];
  int b = blockIdx.z;
  int m0 = blockIdx.x * 128;
  int c0 = blockIdx.y * 128;
  int t = threadIdx.x;
  int w = t >> 6, l = t & 63;
  int cw = w >> 1, mw = w & 1;          // wave's half in c / m
  int lm = l & 15, q8 = (l >> 4) * 8;

  *(float4*)&qs[t * 4] = *(const float4*)&q[b * N + t * 4];

  // per-thread softmax constants for its E row (m_l) / x row (c_l)
  int m_l = t >> 1, nh = t & 1;         // E: row m_l, 16-col half nh
  float km = k[b * N + m0 + m_l];
  float qmv = qmax[b];
  float s0 = qmv + km;
  float M  = fmaxf(s0, 0.01f * s0);
  float k2 = km - M;
  float k3 = 0.01f * km - M;
  float Zp = 0.f;
  const float* xrow = x + ((size_t)b * C + c0 + m_l) * N + nh * 16;

  __syncthreads();

  f32x4 acc[4][4] = {};
  for (int n0 = 0; n0 < N; n0 += 32) {
    // global loads first (latency overlap)
    float4 x0 = *(const float4*)(xrow + n0);
    float4 x1 = *(const float4*)(xrow + n0 + 4);
    float4 x2 = *(const float4*)(xrow + n0 + 8);
    float4 x3 = *(const float4*)(xrow + n0 + 12);
    // E synthesis (16 values, fp32 then fp16)
    float e[16];
#pragma unroll
    for (int jj = 0; jj < 16; ++jj) {
      float qv = qs[n0 + nh * 16 + jj];
      float arg = fmaxf(qv + k2, fmaf(0.01f, qv, k3));
      e[jj] = EXP2(arg);
      Zp += e[jj];
    }
    half8 h0, h1;
#pragma unroll
    for (int jj = 0; jj < 8; ++jj) { h0[jj] = (_Float16)e[jj]; h1[jj] = (_Float16)e[jj + 8]; }

    __syncthreads();  // previous iteration's frag reads complete
    *(half8*)&As[m_l * 40 + nh * 16]     = cvt8(x0, x1);
    *(half8*)&As[m_l * 40 + nh * 16 + 8] = cvt8(x2, x3);
    *(half8*)&Es[m_l * 40 + nh * 16]     = h0;
    *(half8*)&Es[m_l * 40 + nh * 16 + 8] = h1;
    __syncthreads();

    half8 af[4], bf[4];
#pragma unroll
    for (int i = 0; i < 4; ++i)
      af[i] = *(const half8*)&As[(cw * 64 + i * 16 + lm) * 40 + q8];
#pragma unroll
    for (int j = 0; j < 4; ++j)
      bf[j] = *(const half8*)&Es[(mw * 64 + j * 16 + lm) * 40 + q8];
#pragma unroll
    for (int i = 0; i < 4; ++i)
#pragma unroll
      for (int j = 0; j < 4; ++j)
        acc[i][j] = __builtin_amdgcn_mfma_f32_16x16x32_f16(af[i], bf[j], acc[i][j], 0, 0, 0);
  }

  // reduce Z over the two n-halves (adjacent lanes), publish invZ per m-row
  float Z = Zp + __shfl_xor(Zp, 1, 64);
  izs[m_l] = 1.0f / Z;
  __syncthreads();

  float izv[4];
#pragma unroll
  for (int j = 0; j < 4; ++j) izv[j] = izs[mw * 64 + j * 16 + lm];
#pragma unroll
  for (int i = 0; i < 4; ++i) {
    int c_b = c0 + cw * 64 + i * 16 + (l >> 4) * 4;
#pragma unroll
    for (int j = 0; j < 4; ++j) {
      int m_c = m0 + mw * 64 + j * 16 + lm;
      float iz = izv[j];
      half4v h;
      h[0] = (_Float16)(acc[i][j][0] * iz);
      h[1] = (_Float16)(acc[i][j][1] * iz);
      h[2] = (_Float16)(acc[i][j][2] * iz);
      h[3] = (_Float16)(acc[i][j][3] * iz);
      *(half4v*)&aggT[((size_t)b * N + m_c) * C + c_b] = h;
    }
  }
}

// ---------------- K4: gemm_b  out[o][m] = relu(bm[o] + sum_c aggT[m][c]*wm[o][c])
// Block tile: 128 m (M via A=aggT) x 128 o (N via B=wm->fp16), K=c, BK=32.
__global__ __launch_bounds__(256) void gemm_b_kernel(const _Float16* __restrict__ aggT,
    const float* __restrict__ wm, const float* __restrict__ bm,
    float* __restrict__ out) {
  __shared__ __align__(16) _Float16 Am[128 * 40];
  __shared__ __align__(16) _Float16 Wo[128 * 40];
  int b = blockIdx.z;
  int m0 = blockIdx.x * 128;
  int o0 = blockIdx.y * 128;
  int t = threadIdx.x;
  int w = t >> 6, l = t & 63;
  int mw = w >> 1, ow = w & 1;
  int lm = l & 15, q8 = (l >> 4) * 8;
  int row = t >> 2, off8 = (t & 3) * 8;

  f32x4 acc[4][4] = {};
  for (int c0 = 0; c0 < C; c0 += 32) {
    half8 a0 = *(const half8*)&aggT[((size_t)b * N + m0 + row) * C + c0 + off8];
    half8 a1 = *(const half8*)&aggT[((size_t)b * N + m0 + row + 64) * C + c0 + off8];
    float4 w0 = *(const float4*)&wm[(size_t)(o0 + row) * C + c0 + off8];
    float4 w1 = *(const float4*)&wm[(size_t)(o0 + row) * C + c0 + off8 + 4];
    float4 w2 = *(const float4*)&wm[(size_t)(o0 + row + 64) * C + c0 + off8];
    float4 w3 = *(const float4*)&wm[(size_t)(o0 + row + 64) * C + c0 + off8 + 4];
    __syncthreads();
    *(half8*)&Am[row * 40 + off8]        = a0;
    *(half8*)&Am[(row + 64) * 40 + off8] = a1;
    *(half8*)&Wo[row * 40 + off8]        = cvt8(w0, w1);
    *(half8*)&Wo[(row + 64) * 40 + off8] = cvt8(w2, w3);
    __syncthreads();

    half8 af[4], bf[4];
#pragma unroll
    for (int i = 0; i < 4; ++i)
      af[i] = *(const half8*)&Am[(mw * 64 + i * 16 + lm) * 40 + q8];
#pragma unroll
    for (int j = 0; j < 4; ++j)
      bf[j] = *(const half8*)&Wo[(ow * 64 + j * 16 + lm) * 40 + q8];
#pragma unroll
    for (int i = 0; i < 4; ++i)
#pragma unroll
      for (int j = 0; j < 4; ++j)
        acc[i][j] = __builtin_amdgcn_mfma_f32_16x16x32_f16(af[i], bf[j], acc[i][j], 0, 0, 0);
  }

  float bias[4];
#pragma unroll
  for (int j = 0; j < 4; ++j) bias[j] = bm[o0 + ow * 64 + j * 16 + lm];
#pragma unroll
  for (int i = 0; i < 4; ++i) {
    int m_b = m0 + mw * 64 + i * 16 + (l >> 4) * 4;
#pragma unroll
    for (int j = 0; j < 4; ++j) {
      int o_c = o0 + ow * 64 + j * 16 + lm;
      float4 r;
      r.x = fmaxf(acc[i][j][0] + bias[j], 0.f);
      r.y = fmaxf(acc[i][j][1] + bias[j], 0.f);
      r.z = fmaxf(acc[i][j][2] + bias[j], 0.f);
      r.w = fmaxf(acc[i][j][3] + bias[j], 0.f);
      *(float4*)&out[((size_t)b * O + o_c) * N + m_b] = r;
    }
  }
}

extern "C" void kernel_launch(void* const* d_in, const int* in_sizes, int n_in,
                              void* d_out, int out_size, void* d_ws, size_t ws_size,
                              hipStream_t stream) {
  const float* x  = (const float*)d_in[0];
  const float* wq = (const float*)d_in[1];
  const float* wk = (const float*)d_in[2];
  const float* wm = (const float*)d_in[3];
  const float* bm = (const float*)d_in[4];
  float* out = (float*)d_out;

  // ws: q[B*N] | k[B*N] | qmax[64] (f32)  | aggT[B*N*C] fp16  (~33.8 MB total)
  float* q    = (float*)d_ws;
  float* k    = q + B * N;
  float* qmax = k + B * N;
  _Float16* aggT = (_Float16*)(qmax + 64);

  qk_kernel<<<dim3(N / 64, B), 256, 0, stream>>>(x, wq, wk, q, k);
  qmax_kernel<<<dim3(B), 256, 0, stream>>>(q, qmax);
  gemm_a_kernel<<<dim3(N / 128, C / 128, B), 256, 0, stream>>>(x, q, k, qmax, aggT);
  gemm_b_kernel<<<dim3(N / 128, O / 128, B), 256, 0, stream>>>(aggT, wm, bm, out);
}

// Round 4
// 228.884 us; speedup vs baseline: 4.0003x; 1.0685x over previous
//
#include <hip/hip_runtime.h>

// GATLayer on MI355X — Y-association, MFMA fp16.
//   q = (wq.x)*log2e, k = (wk.x)*log2e                    [qk_kernel]
//   qmax_b = max_n q                                       [qmax_kernel]
//   Y[o][n] = sum_c wm[o][c] x[c][n]  (fp16)               [gemm_y]
//   E[m][n] = 2^(leaky(q_n+k_m) - M_m), M_m = leaky(qmax+k_m)  (synthesized)
//   out[o][m] = relu(bm[o] + invZ_m * sum_n Y[o][n]*E[m][n])  [gemm_out]
// Z accumulated inside gemm_out (thread pair covers each m-row's n).
// Grid orderings put same-reuse-strip blocks at linear stride ≡0 (mod 8)
// so they share an XCD L2 (block->XCD round-robin heuristic).

constexpr int B = 32, C = 512, N = 1024, O = 512;
constexpr float L2E = 1.4426950408889634f;

typedef _Float16 half8 __attribute__((ext_vector_type(8)));
typedef _Float16 half4v __attribute__((ext_vector_type(4)));
typedef _Float16 half2v __attribute__((ext_vector_type(2)));
typedef float f32x4 __attribute__((ext_vector_type(4)));

#if __has_builtin(__builtin_amdgcn_exp2f)
#define EXP2(x) __builtin_amdgcn_exp2f(x)
#else
#define EXP2(x) exp2f(x)
#endif

__device__ __forceinline__ half8 cvt8(float4 a, float4 b) {
  half8 h;
  h[0] = (_Float16)a.x; h[1] = (_Float16)a.y; h[2] = (_Float16)a.z; h[3] = (_Float16)a.w;
  h[4] = (_Float16)b.x; h[5] = (_Float16)b.y; h[6] = (_Float16)b.z; h[7] = (_Float16)b.w;
  return h;
}

// ---------------- K1: q,k (scaled by log2e) ----------------
__global__ __launch_bounds__(256) void qk_kernel(const float* __restrict__ x,
    const float* __restrict__ wq, const float* __restrict__ wk,
    float* __restrict__ q, float* __restrict__ k) {
  int b = blockIdx.y;
  int l = threadIdx.x & 63;
  int cq = threadIdx.x >> 6;
  int n = blockIdx.x * 64 + l;
  const float* xp  = x + ((size_t)b * C + cq * 128) * N + n;
  const float* wqp = wq + cq * 128;
  const float* wkp = wk + cq * 128;
  float aq = 0.f, ak = 0.f;
#pragma unroll 8
  for (int c = 0; c < 128; ++c) {
    float v = xp[(size_t)c * N];
    aq += wqp[c] * v;
    ak += wkp[c] * v;
  }
  __shared__ float rq[4][64], rk[4][64];
  rq[cq][l] = aq;
  rk[cq][l] = ak;
  __syncthreads();
  if (threadIdx.x < 64) {
    float sq = (rq[0][l] + rq[1][l]) + (rq[2][l] + rq[3][l]);
    float sk = (rk[0][l] + rk[1][l]) + (rk[2][l] + rk[3][l]);
    q[b * N + blockIdx.x * 64 + l] = L2E * sq;
    k[b * N + blockIdx.x * 64 + l] = L2E * sk;
  }
}

// ---------------- K2: qmax[b] ----------------
__global__ __launch_bounds__(256) void qmax_kernel(const float* __restrict__ q,
                                                   float* __restrict__ qmax) {
  int b = blockIdx.x;
  int tid = threadIdx.x;
  float m = -1e30f;
  for (int n = tid; n < N; n += 256) m = fmaxf(m, q[b * N + n]);
#pragma unroll
  for (int off = 32; off > 0; off >>= 1) m = fmaxf(m, __shfl_down(m, off, 64));
  __shared__ float red[4];
  if ((tid & 63) == 0) red[tid >> 6] = m;
  __syncthreads();
  if (tid == 0) qmax[b] = fmaxf(fmaxf(red[0], red[1]), fmaxf(red[2], red[3]));
}

// ---------------- K3: gemm_y  Yt[b][o][n] = sum_c wm[o][c] x[b][c][n] --------
// Block: 128n (A/M via xT) x 128o (B/N via wm), K=c BK=32. Xs stores c-PAIRS
// as half2 words so A-fragments are ds_read_b32 (k-pairs), S=130 words.
__global__ __launch_bounds__(256) void gemm_y_kernel(const float* __restrict__ x,
    const float* __restrict__ wm, _Float16* __restrict__ Yt) {
  __shared__ half2v Xs[16 * 130];                 // (c/2, n): low=even c
  __shared__ __align__(16) _Float16 Ws[128 * 40]; // [o][c] K-major
  int b  = blockIdx.y;
  int n0 = blockIdx.x * 128;
  int o0 = blockIdx.z * 128;
  int t = threadIdx.x;
  int w = t >> 6, l = t & 63;
  int nw = w >> 1, ow = w & 1;
  int lm = l & 15, q8 = (l >> 4) * 8, q4 = (l >> 4) * 4;

  int cp = t >> 4, ng = t & 15;           // Xs staging: rows 2cp,2cp+1, n=ng*8..+7
  int wrow = t >> 2, woff = (t & 3) * 8;  // Ws staging

  f32x4 acc[4][4] = {};
  for (int c0 = 0; c0 < C; c0 += 32) {
    const float* xr = x + ((size_t)b * C + c0 + 2 * cp) * N + n0 + ng * 8;
    float4 a0 = *(const float4*)(xr);
    float4 a1 = *(const float4*)(xr + 4);
    float4 b0 = *(const float4*)(xr + N);
    float4 b1 = *(const float4*)(xr + N + 4);
    const float* wr = wm + (size_t)(o0 + wrow) * C + c0 + woff;
    float4 w0 = *(const float4*)(wr);
    float4 w1 = *(const float4*)(wr + 4);
    float4 w2 = *(const float4*)(wr + (size_t)64 * C);
    float4 w3 = *(const float4*)(wr + (size_t)64 * C + 4);
    __syncthreads();
    {
      half2v* xp = &Xs[cp * 130 + ng * 8];
      xp[0] = half2v{(_Float16)a0.x, (_Float16)b0.x};
      xp[1] = half2v{(_Float16)a0.y, (_Float16)b0.y};
      xp[2] = half2v{(_Float16)a0.z, (_Float16)b0.z};
      xp[3] = half2v{(_Float16)a0.w, (_Float16)b0.w};
      xp[4] = half2v{(_Float16)a1.x, (_Float16)b1.x};
      xp[5] = half2v{(_Float16)a1.y, (_Float16)b1.y};
      xp[6] = half2v{(_Float16)a1.z, (_Float16)b1.z};
      xp[7] = half2v{(_Float16)a1.w, (_Float16)b1.w};
      *(half8*)&Ws[wrow * 40 + woff]        = cvt8(w0, w1);
      *(half8*)&Ws[(wrow + 64) * 40 + woff] = cvt8(w2, w3);
    }
    __syncthreads();

    half8 af[4], bf[4];
#pragma unroll
    for (int i = 0; i < 4; ++i) {
      int nrow = nw * 64 + i * 16 + lm;
#pragma unroll
      for (int jp = 0; jp < 4; ++jp) {
        half2v p = Xs[(q4 + jp) * 130 + nrow];
        af[i][2 * jp]     = p[0];
        af[i][2 * jp + 1] = p[1];
      }
    }
#pragma unroll
    for (int j = 0; j < 4; ++j)
      bf[j] = *(const half8*)&Ws[(ow * 64 + j * 16 + lm) * 40 + q8];
#pragma unroll
    for (int i = 0; i < 4; ++i)
#pragma unroll
      for (int j = 0; j < 4; ++j)
        acc[i][j] = __builtin_amdgcn_mfma_f32_16x16x32_f16(af[i], bf[j], acc[i][j], 0, 0, 0);
  }

#pragma unroll
  for (int i = 0; i < 4; ++i) {
    int n_b = n0 + nw * 64 + i * 16 + (l >> 4) * 4;
#pragma unroll
    for (int j = 0; j < 4; ++j) {
      int o_c = o0 + ow * 64 + j * 16 + lm;
      half4v h;
      h[0] = (_Float16)acc[i][j][0];
      h[1] = (_Float16)acc[i][j][1];
      h[2] = (_Float16)acc[i][j][2];
      h[3] = (_Float16)acc[i][j][3];
      *(half4v*)&Yt[((size_t)b * O + o_c) * N + n_b] = h;
    }
  }
}

// ---------------- K4: gemm_out  out[o][m] = relu(bm + invZ_m sum_n Y[o][n]E[m][n])
// Block: 128m (A/M via synthesized E) x 128o (B/N via Yt rows), K=n BK=32.
__global__ __launch_bounds__(256) void gemm_out_kernel(const _Float16* __restrict__ Yt,
    const float* __restrict__ q, const float* __restrict__ k,
    const float* __restrict__ qmax, const float* __restrict__ bm,
    float* __restrict__ out) {
  __shared__ __align__(16) float qs[N];
  __shared__ __align__(16) _Float16 Es[128 * 40];
  __shared__ __align__(16) _Float16 Ys[128 * 40];
  __shared__ float izs[128];
  int b  = blockIdx.y;
  int o0 = blockIdx.x * 128;
  int m0 = blockIdx.z * 128;
  int t = threadIdx.x;
  int w = t >> 6, l = t & 63;
  int mw = w >> 1, ow = w & 1;
  int lm = l & 15, q8 = (l >> 4) * 8;

  *(float4*)&qs[t * 4] = *(const float4*)&q[b * N + t * 4];

  int m_l = t >> 1, nh = t & 1;       // E row, 16-col half
  float km = k[b * N + m0 + m_l];
  float qmv = qmax[b];
  float s0 = qmv + km;
  float M  = fmaxf(s0, 0.01f * s0);
  float k2 = km - M;
  float k3 = fmaf(0.01f, km, -M);
  float Zp = 0.f;
  int yrow = t >> 2, yoff = (t & 3) * 8;
  __syncthreads();

  f32x4 acc[4][4] = {};
  for (int n0k = 0; n0k < N; n0k += 32) {
    half8 y0 = *(const half8*)&Yt[((size_t)b * O + o0 + yrow) * N + n0k + yoff];
    half8 y1 = *(const half8*)&Yt[((size_t)b * O + o0 + yrow + 64) * N + n0k + yoff];
    float4 qv0 = *(const float4*)&qs[n0k + nh * 16];
    float4 qv1 = *(const float4*)&qs[n0k + nh * 16 + 4];
    float4 qv2 = *(const float4*)&qs[n0k + nh * 16 + 8];
    float4 qv3 = *(const float4*)&qs[n0k + nh * 16 + 12];
    float ev[16];
    {
      const float* qq = (const float*)&qv0;  // qv0..qv3 contiguous? not guaranteed
      float tmp[16] = {qv0.x, qv0.y, qv0.z, qv0.w, qv1.x, qv1.y, qv1.z, qv1.w,
                       qv2.x, qv2.y, qv2.z, qv2.w, qv3.x, qv3.y, qv3.z, qv3.w};
      (void)qq;
#pragma unroll
      for (int jj = 0; jj < 16; ++jj) {
        float arg = fmaxf(tmp[jj] + k2, fmaf(0.01f, tmp[jj], k3));
        ev[jj] = EXP2(arg);
        Zp += ev[jj];
      }
    }
    half8 h0, h1;
#pragma unroll
    for (int jj = 0; jj < 8; ++jj) { h0[jj] = (_Float16)ev[jj]; h1[jj] = (_Float16)ev[jj + 8]; }

    __syncthreads();
    *(half8*)&Es[m_l * 40 + nh * 16]     = h0;
    *(half8*)&Es[m_l * 40 + nh * 16 + 8] = h1;
    *(half8*)&Ys[yrow * 40 + yoff]        = y0;
    *(half8*)&Ys[(yrow + 64) * 40 + yoff] = y1;
    __syncthreads();

    half8 af[4], bf[4];
#pragma unroll
    for (int i = 0; i < 4; ++i)
      af[i] = *(const half8*)&Es[(mw * 64 + i * 16 + lm) * 40 + q8];
#pragma unroll
    for (int j = 0; j < 4; ++j)
      bf[j] = *(const half8*)&Ys[(ow * 64 + j * 16 + lm) * 40 + q8];
#pragma unroll
    for (int i = 0; i < 4; ++i)
#pragma unroll
      for (int j = 0; j < 4; ++j)
        acc[i][j] = __builtin_amdgcn_mfma_f32_16x16x32_f16(af[i], bf[j], acc[i][j], 0, 0, 0);
  }

  float Z = Zp + __shfl_xor(Zp, 1, 64);
  izs[m_l] = 1.0f / Z;
  __syncthreads();

#pragma unroll
  for (int i = 0; i < 4; ++i) {
    int m_b = m0 + mw * 64 + i * 16 + (l >> 4) * 4;
    float4 iz4 = *(const float4*)&izs[mw * 64 + i * 16 + (l >> 4) * 4];
#pragma unroll
    for (int j = 0; j < 4; ++j) {
      int o_c = o0 + ow * 64 + j * 16 + lm;
      float bias = bm[o_c];
      float4 r;
      r.x = fmaxf(fmaf(acc[i][j][0], iz4.x, bias), 0.f);
      r.y = fmaxf(fmaf(acc[i][j][1], iz4.y, bias), 0.f);
      r.z = fmaxf(fmaf(acc[i][j][2], iz4.z, bias), 0.f);
      r.w = fmaxf(fmaf(acc[i][j][3], iz4.w, bias), 0.f);
      *(float4*)&out[((size_t)b * O + o_c) * N + m_b] = r;
    }
  }
}

extern "C" void kernel_launch(void* const* d_in, const int* in_sizes, int n_in,
                              void* d_out, int out_size, void* d_ws, size_t ws_size,
                              hipStream_t stream) {
  const float* x  = (const float*)d_in[0];
  const float* wq = (const float*)d_in[1];
  const float* wk = (const float*)d_in[2];
  const float* wm = (const float*)d_in[3];
  const float* bm = (const float*)d_in[4];
  float* out = (float*)d_out;

  // ws: q[B*N] | k[B*N] | qmax[64] (f32) | Yt[B*O*N] fp16   (~32.3 MiB)
  float* q    = (float*)d_ws;
  float* k    = q + B * N;
  float* qmax = k + B * N;
  _Float16* Yt = (_Float16*)(qmax + 64);

  qk_kernel<<<dim3(N / 64, B), 256, 0, stream>>>(x, wq, wk, q, k);
  qmax_kernel<<<dim3(B), 256, 0, stream>>>(q, qmax);
  // gemm_y: x-strip (per n-tile,b) reused by o-blocks at linear stride 256 (same XCD)
  gemm_y_kernel<<<dim3(N / 128, B, O / 128), 256, 0, stream>>>(x, wm, Yt);
  // gemm_out: Y-strip (per o-tile,b) reused by m-blocks at linear stride 128 (same XCD)
  gemm_out_kernel<<<dim3(O / 128, B, N / 128), 256, 0, stream>>>(Yt, q, k, qmax, bm, out);
}